// Round 11
// baseline (196.258 us; speedup 1.0000x reference)
//
#include <hip/hip_runtime.h>
#include <math.h>

// Problem constants (ProbAttention: B=4, L=4096, H=8, D=64, S=U=ceil(ln L)=9)
#define B_ 4
#define L_ 4096
#define H_ 8
#define D_ 64
#define S_ 9
#define U_ 9
#define VC_ 64   // vmean stage-1 chunks per batch
#define CC_ 16   // ctx    chunks per (b,h)  (chunk = 256 keys)
#define TKC_ 8   // topk stage-1 chunks per (b,h)
#define KCH_ 32  // scores: keys per block (all 8 heads at once)
#define NCHK_ (L_ / KCH_)           // 128 score chunks per (b,h) row
#define SCB_ (B_ * NCHK_)           // 512 scores blocks

#define VMBLK_ 256                  // vmean1 blocks (front of grid: streaming)
#define MBLK_ 4096                  // kernel_M blocks: B*L waves, 4 waves/block
#define FILLBLK_ 8192               // fill blocks

__device__ __forceinline__ float dot4(const float4& a, const float4& b) {
    return a.x * b.x + a.y * b.y + a.z * b.z + a.w * b.w;
}

// ---------------------------------------------------------------------------
// K1: fused vmean1 (blocks 0..255, streaming) + kernel_M (blocks 256..4351).
// kernel_M: one wave per (b,l); 8 heads of a K row are 2048B contiguous.
// r3-r5: ILP/occupancy variants invariant at 43.5-44.5us -> random-gather
// service-rate bound. r10 experiment: XCD-PINNED BATCHES — blocks are
// dispatched round-robin over the 8 XCDs, so map batch b to XCD pair
// {2b,2b+1} (b = (blk&7)>>1). Per-XCD K working set drops 33.5MB -> 8.4MB
// against the 4MB private L2: K re-fetch traffic past L2 should halve.
// Verification signal: FETCH_SIZE 137MB -> ~105MB. If unchanged, kernel_M
// is at its structural floor (declare roofline).
// ---------------------------------------------------------------------------
__global__ void __launch_bounds__(256, 4)
kernel_M_vmean(const float* __restrict__ Q, const float* __restrict__ K,
               const int* __restrict__ idx, float* __restrict__ M,
               const float* __restrict__ V, float* __restrict__ vpart) {
    if (blockIdx.x < VMBLK_) {
        int blk = blockIdx.x;
        int c = blk & (VC_ - 1), b = blk >> 6;
        int col = threadIdx.x & 127;
        int lp  = threadIdx.x >> 7;
        const int CHUNK = L_ / VC_;
        const float4* base = (const float4*)(V + (size_t)b * L_ * H_ * D_);
        float4 acc = make_float4(0.f, 0.f, 0.f, 0.f);
        for (int l = c * CHUNK + lp; l < (c + 1) * CHUNK; l += 2) {
            float4 v = base[(size_t)l * 128 + col];
            acc.x += v.x; acc.y += v.y; acc.z += v.z; acc.w += v.w;
        }
        __shared__ float4 red[256];
        red[threadIdx.x] = acc;
        __syncthreads();
        if (lp == 0) {
            float4 o = red[threadIdx.x + 128];
            acc.x += o.x; acc.y += o.y; acc.z += o.z; acc.w += o.w;
            ((float4*)vpart)[(size_t)blk * 128 + col] = acc;
        }
        return;
    }
    int t = threadIdx.x;
    int wid = t >> 6, lane = t & 63;
    // XCD-pinned batch mapping: XCD = n&7 handles batch (n&7)>>1.
    int n = blockIdx.x - VMBLK_;          // 0..4095
    int x = n & 7;                        // XCD id (round-robin dispatch)
    int b = __builtin_amdgcn_readfirstlane(x >> 1);
    int lblk = ((n >> 3) << 1) | (x & 1); // 0..1023 within batch
    int l = __builtin_amdgcn_readfirstlane(lblk * 4 + wid);

    int ki[S_];
#pragma unroll
    for (int s = 0; s < S_; ++s) ki[s] = idx[l * S_ + s];

    const float4* qb = (const float4*)(Q + (size_t)(b * L_ + l) * (H_ * D_));
    float4 q0 = qb[2 * lane];
    float4 q1 = qb[2 * lane + 1];

    const float* Kb = K + (size_t)b * L_ * (H_ * D_);

    float4 ka[S_], kc[S_];
#pragma unroll
    for (int s = 0; s < S_; ++s) {
        const float4* kp = (const float4*)(Kb + (size_t)ki[s] * (H_ * D_));
        ka[s] = kp[2 * lane];
        kc[s] = kp[2 * lane + 1];
    }

    float mx = -INFINITY, sm = 0.0f;
#pragma unroll
    for (int s = 0; s < S_; ++s) {
        float d = dot4(q0, ka[s]) + dot4(q1, kc[s]);
        d += __shfl_xor(d, 1);
        d += __shfl_xor(d, 2);
        d += __shfl_xor(d, 4);
        mx = fmaxf(mx, d);
        sm += d;
    }
    if ((lane & 7) == 0) {
        int h = lane >> 3;
        M[((size_t)(b * H_ + h) << 12) + l] = mx - sm * (1.0f / (float)L_);
    }
}

// ---------------------------------------------------------------------------
// Top-k stage 1 (value desc, index asc) — matches jax.lax.top_k.
// 256 blocks: wide grid (r9 lesson — do NOT narrow this for launch savings).
// ---------------------------------------------------------------------------
#define CSWAP(a, b)                                                          \
    if (v[b] > v[a] || (v[b] == v[a] && id[b] < id[a])) {                    \
        float tv = v[a]; v[a] = v[b]; v[b] = tv;                             \
        int ti = id[a]; id[a] = id[b]; id[b] = ti;                           \
    }

__global__ void kernel_topk1(const float* __restrict__ M,
                             float* __restrict__ cand_v, int* __restrict__ cand_i) {
    int bh = blockIdx.x >> 3;
    int chunk = blockIdx.x & (TKC_ - 1);
    int lane = threadIdx.x;
    const float* Ms = M + ((size_t)bh << 12);

    float v[8]; int id[8];
#pragma unroll
    for (int c = 0; c < 8; ++c) {
        int gi = chunk * 512 + lane + 64 * c;
        v[c] = Ms[gi]; id[c] = gi;
    }
    CSWAP(0,1) CSWAP(2,3) CSWAP(4,5) CSWAP(6,7)
    CSWAP(0,2) CSWAP(1,3) CSWAP(4,6) CSWAP(5,7)
    CSWAP(1,2) CSWAP(5,6)
    CSWAP(0,4) CSWAP(1,5) CSWAP(2,6) CSWAP(3,7)
    CSWAP(2,4) CSWAP(3,5)
    CSWAP(1,2) CSWAP(3,4) CSWAP(5,6)

    float* cv = cand_v + (size_t)blockIdx.x * U_;
    int*   ci = cand_i + (size_t)blockIdx.x * U_;
#pragma unroll
    for (int r = 0; r < U_; ++r) {
        float bv = v[0]; int bi = id[0];
#pragma unroll
        for (int off = 1; off < 64; off <<= 1) {
            float ov = __shfl_xor(bv, off);
            int   oi = __shfl_xor(bi, off);
            if (ov > bv || (ov == bv && oi < bi)) { bv = ov; bi = oi; }
        }
        if (lane == 0) { cv[r] = bv; ci[r] = bi; }
        if (id[0] == bi) {
#pragma unroll
            for (int c = 0; c < 7; ++c) { v[c] = v[c+1]; id[c] = id[c+1]; }
            v[7] = -INFINITY; id[7] = 0x7fffffff;
        }
    }
}

// ---------------------------------------------------------------------------
// K3: fused topk2 (blocks 0..31) + vmean2 (blocks 32..63). 64 threads.
// ---------------------------------------------------------------------------
__global__ void kernel_small(const float* __restrict__ cand_v, const int* __restrict__ cand_i,
                             int* __restrict__ Mtop, const float* __restrict__ vpart,
                             float* __restrict__ vmean) {
    if (blockIdx.x >= 32) {
        int bh = blockIdx.x - 32;
        int h = bh & (H_ - 1), b = bh >> 3;
        int d = threadIdx.x;
        float s = 0.0f;
        for (int c = 0; c < VC_; ++c)
            s += vpart[(size_t)(b * VC_ + c) * (H_ * D_) + h * D_ + d];
        vmean[bh * D_ + d] = s * (1.0f / (float)L_);
        return;
    }
    int bh = blockIdx.x;
    int lane = threadIdx.x;
    const float* cv = cand_v + (size_t)bh * (TKC_ * U_);
    const int*   ci = cand_i + (size_t)bh * (TKC_ * U_);

    float v[2]; int id[2];
    v[0] = cv[lane]; id[0] = ci[lane];
    if (lane < TKC_ * U_ - 64) { v[1] = cv[64 + lane]; id[1] = ci[64 + lane]; }
    else { v[1] = -INFINITY; id[1] = 0x7fffffff; }
    CSWAP(0,1)

#pragma unroll
    for (int r = 0; r < U_; ++r) {
        float bv = v[0]; int bi = id[0];
#pragma unroll
        for (int off = 1; off < 64; off <<= 1) {
            float ov = __shfl_xor(bv, off);
            int   oi = __shfl_xor(bi, off);
            if (ov > bv || (ov == bv && oi < bi)) { bv = ov; bi = oi; }
        }
        if (lane == 0) Mtop[bh * U_ + r] = bi;
        if (id[0] == bi) { v[0] = v[1]; id[0] = id[1]; v[1] = -INFINITY; id[1] = 0x7fffffff; }
    }
}

// ---------------------------------------------------------------------------
// K4: fused fill (blocks 0..8191) + scores_raw (blocks 8192..8703).
// scores_raw: one block per (b, 32-key chunk), ALL 8 HEADS per wave (K rows
// read as contiguous 2KB). Emits per-(row,chunk) softmax stats (max, sumexp)
// so softmax finalization fuses into the ctx kernel.
// ---------------------------------------------------------------------------
__global__ void __launch_bounds__(256, 4)
kernel_fill_scores(float* __restrict__ out, const float* __restrict__ vmean,
                   const float* __restrict__ Q, const float* __restrict__ K,
                   const int* __restrict__ Mtop, float* __restrict__ raw,
                   float* __restrict__ stats) {
    if (blockIdx.x < FILLBLK_) {
        int i = blockIdx.x * 256 + threadIdx.x;
        int d4 = i & 15;
        int h  = (i >> 4) & (H_ - 1);
        int b  = i >> (4 + 3 + 12);
        ((float4*)out)[i] = ((const float4*)vmean)[(b * H_ + h) * 16 + d4];
        return;
    }
    int n = blockIdx.x - FILLBLK_;       // 0..511
    int b = n >> 7;                      // NCHK_=128 chunks per batch
    int chunk = n & 127;
    int k0 = chunk * KCH_;

    int t = threadIdx.x;
    int w = t >> 6, lane = t & 63;
    int h = lane >> 3, dq = lane & 7;
    int bh = b * H_ + h;

    float4 q0[U_], q1[U_];
#pragma unroll
    for (int u = 0; u < U_; ++u) {
        int mi = Mtop[bh * U_ + u];
        const float4* qp = (const float4*)(Q + (size_t)((b * L_ + mi) * H_ + h) * D_);
        q0[u] = qp[2 * dq];
        q1[u] = qp[2 * dq + 1];
    }

    __shared__ float sc[H_][U_][KCH_ + 1];   // +1 pad: spread h-stride over banks

    const float* Kb = K + (size_t)b * L_ * (H_ * D_);
    const float4* kp = (const float4*)(Kb + (size_t)(k0 + w * 8) * (H_ * D_));
    float4 kv0 = kp[2 * lane], kv1 = kp[2 * lane + 1];
#pragma unroll
    for (int i = 0; i < 8; ++i) {
        int kloc = w * 8 + i;
        float4 nv0, nv1;
        if (i < 7) {               // one-deep register prefetch of next row
            const float4* np = (const float4*)(Kb + (size_t)(k0 + kloc + 1) * (H_ * D_));
            nv0 = np[2 * lane]; nv1 = np[2 * lane + 1];
        }
        float p[U_];
#pragma unroll
        for (int u = 0; u < U_; ++u) {
            float d = dot4(q0[u], kv0) + dot4(q1[u], kv1);
            d += __shfl_xor(d, 1);
            d += __shfl_xor(d, 2);
            d += __shfl_xor(d, 4);
            p[u] = d;
        }
        // lane dq writes u=dq (static-index select chain, no scratch)
        float val = p[0];
#pragma unroll
        for (int u = 1; u < 8; ++u) val = (dq == u) ? p[u] : val;
        sc[h][dq][kloc] = val;
        if (dq == 0) sc[h][8][kloc] = p[8];
        kv0 = nv0; kv1 = nv1;
    }
    __syncthreads();

    // coalesced write-out: 8h*9u*32k = 2304 floats, 32-float runs per (h,u)
#pragma unroll
    for (int r = 0; r < 9; ++r) {
        int j = r * 256 + t;
        int kloc = j & 31;
        int hu = j >> 5;                 // 0..71
        int h2 = hu / U_, u2 = hu - h2 * U_;
        raw[((size_t)(b * H_ + h2) * U_ + u2) * L_ + k0 + kloc] =
            sc[h2][u2][kloc] * 0.125f;
    }

    // per-(row,chunk) softmax stats over the 32 scaled scores
    if (t < H_ * U_) {
        int h2 = t / U_, u2 = t - h2 * U_;
        float mxs = -INFINITY;
#pragma unroll
        for (int k = 0; k < KCH_; ++k) mxs = fmaxf(mxs, sc[h2][u2][k]);
        mxs *= 0.125f;
        float se = 0.0f;
#pragma unroll
        for (int k = 0; k < KCH_; ++k) se += expf(sc[h2][u2][k] * 0.125f - mxs);
        ((float2*)stats)[(size_t)((b * H_ + h2) * U_ + u2) * NCHK_ + chunk] =
            make_float2(mxs, se);
    }
}

// ---------------------------------------------------------------------------
// K6': ctx fused with SOFTMAX (replaces separate softmax + old ctxf).
// 512 blocks (wide — r9 lesson). Phase A: flash-combine 128 chunk stats per
// row -> (gmax, 1/gsum); u-loop covers row 8 (r6 fix). Phase B: attn tile =
// exp(raw-gmax)/gsum -> LDS + attn output. Phase C: ctx partials.
// ---------------------------------------------------------------------------
__global__ void kernel_ctxf(float* __restrict__ attn, const float* __restrict__ stats,
                            const float* __restrict__ V, float* __restrict__ cpart) {
    int n = blockIdx.x;
    int x = n & 7, m = n >> 3;
    int chunk = m & (CC_ - 1);
    int bh = (m >> 4) * 8 + x;       // CC_ = 16
    int h = bh & (H_ - 1), b = bh >> 3;
    int k0 = chunk * (L_ / CC_);     // 256 keys

    int t = threadIdx.x;

    // ---- Phase A: per-row global (max, 1/sum) from 128 chunk stats ----
    __shared__ float2 gstat[U_];
    int j = t & 31;
    for (int u = t >> 5; u < U_; u += 8) {   // 8 groups of 32 lanes; u=8 on 2nd pass
        const float2* srow = (const float2*)stats + (size_t)(bh * U_ + u) * NCHK_;
        float2 a = srow[j];
        float mm = a.x, ss = a.y;
#pragma unroll
        for (int c = 1; c < 4; ++c) {
            float2 b2 = srow[j + 32 * c];
            float nm = fmaxf(mm, b2.x);
            ss = ss * expf(mm - nm) + b2.y * expf(b2.x - nm);
            mm = nm;
        }
#pragma unroll
        for (int off = 1; off < 32; off <<= 1) {
            float om = __shfl_xor(mm, off, 32);
            float os = __shfl_xor(ss, off, 32);
            float nm = fmaxf(mm, om);
            ss = ss * expf(mm - nm) + os * expf(om - nm);
            mm = nm;
        }
        if (j == 0) gstat[u] = make_float2(mm, 1.0f / ss);
    }
    __syncthreads();

    // ---- Phase B: materialize attn tile (9 x 256) in LDS + write output ----
    __shared__ float attn_s[U_][256];
    float* arow = attn + (size_t)bh * U_ * L_ + k0;
#pragma unroll
    for (int u = 0; u < U_; ++u) {
        float xv = arow[(size_t)u * L_ + t];
        float av = expf(xv - gstat[u].x) * gstat[u].y;
        attn_s[u][t] = av;
        arow[(size_t)u * L_ + t] = av;
    }
    __syncthreads();

    // ---- Phase C: ctx partial accumulation (attn from LDS broadcast) ----
    int g = t >> 6, lane = t & 63;
    int kl = lane >> 4, d4 = lane & 15;

    float4 acc[U_];
#pragma unroll
    for (int u = 0; u < U_; ++u) acc[u] = make_float4(0.f, 0.f, 0.f, 0.f);

    for (int i = 0; i < 16; ++i) {
        int kloc = (g * 4 + kl) + 16 * i;
        int k = k0 + kloc;
        float4 vv = *(const float4*)(V + (size_t)((b * L_ + k) * H_ + h) * D_ + 4 * d4);
        float av[U_];
#pragma unroll
        for (int u = 0; u < U_; ++u) av[u] = attn_s[u][kloc];
#pragma unroll
        for (int u = 0; u < U_; ++u) {
            acc[u].x += av[u] * vv.x; acc[u].y += av[u] * vv.y;
            acc[u].z += av[u] * vv.z; acc[u].w += av[u] * vv.w;
        }
    }
    // reduce over kl (lanes 16,32 apart)
#pragma unroll
    for (int u = 0; u < U_; ++u) {
        acc[u].x += __shfl_xor(acc[u].x, 16); acc[u].y += __shfl_xor(acc[u].y, 16);
        acc[u].z += __shfl_xor(acc[u].z, 16); acc[u].w += __shfl_xor(acc[u].w, 16);
        acc[u].x += __shfl_xor(acc[u].x, 32); acc[u].y += __shfl_xor(acc[u].y, 32);
        acc[u].z += __shfl_xor(acc[u].z, 32); acc[u].w += __shfl_xor(acc[u].w, 32);
    }
    __shared__ float4 red[U_][4][16];
    if (kl == 0) {
#pragma unroll
        for (int u = 0; u < U_; ++u) red[u][g][d4] = acc[u];
    }
    __syncthreads();
    if (t < U_ * 16) {
        int u = t >> 4, dd = t & 15;
        float4 s0 = red[u][0][dd], s1 = red[u][1][dd];
        float4 s2 = red[u][2][dd], s3 = red[u][3][dd];
        float4 s = make_float4(s0.x + s1.x + s2.x + s3.x, s0.y + s1.y + s2.y + s3.y,
                               s0.z + s1.z + s2.z + s3.z, s0.w + s1.w + s2.w + s3.w);
        ((float4*)cpart)[((size_t)(bh * CC_ + chunk) * U_ + u) * 16 + dd] = s;
    }
}

// K7: combine + scatter. grid = B*H*U (288), 64 threads.
__global__ void kernel_ctx2(const float* __restrict__ cpart, const int* __restrict__ Mtop,
                            float* __restrict__ out) {
    int row = blockIdx.x;
    int u = row % U_, bh = row / U_;
    int h = bh & (H_ - 1), b = bh >> 3;
    int d = threadIdx.x;
    float s = 0.0f;
#pragma unroll
    for (int c = 0; c < CC_; ++c)
        s += cpart[((size_t)(bh * CC_ + c) * U_ + u) * 64 + d];
    int l = Mtop[bh * U_ + u];
    out[(size_t)((b * L_ + l) * H_ + h) * D_ + d] = s;
}

extern "C" void kernel_launch(void* const* d_in, const int* in_sizes, int n_in,
                              void* d_out, int out_size, void* d_ws, size_t ws_size,
                              hipStream_t stream) {
    const float* Q   = (const float*)d_in[0];
    const float* K   = (const float*)d_in[1];
    const float* V   = (const float*)d_in[2];
    const int*   idx = (const int*)d_in[3];

    float* ctx_out  = (float*)d_out;                               // B*L*H*D
    float* attn_out = (float*)d_out + (size_t)B_ * L_ * H_ * D_;   // B*H*U*L

    // workspace (floats): M | vpart | vmean | cpart | cand_v | cand_i | Mtop | stats
    float* M      = (float*)d_ws;                                   // 131072
    float* vpart  = M + (size_t)B_ * H_ * L_;                       // 131072
    float* vmean  = vpart + (size_t)B_ * VC_ * H_ * D_;             // 2048
    float* cpart  = vmean + B_ * H_ * D_;                           // 294912
    float* cand_v = cpart + (size_t)32 * CC_ * U_ * 64;             // 2304
    int*   cand_i = (int*)(cand_v + 32 * TKC_ * U_);                // 2304
    int*   Mtop   = cand_i + 32 * TKC_ * U_;                        // 288
    float* stats  = (float*)(Mtop + 32 * U_);                       // 73728

    kernel_M_vmean<<<VMBLK_ + MBLK_, 256, 0, stream>>>(Q, K, idx, M, V, vpart);
    kernel_topk1<<<B_ * H_ * TKC_, 64, 0, stream>>>(M, cand_v, cand_i);
    kernel_small<<<64, 64, 0, stream>>>(cand_v, cand_i, Mtop, vpart, vmean);
    kernel_fill_scores<<<FILLBLK_ + SCB_, 256, 0, stream>>>(ctx_out, vmean, Q, K, Mtop,
                                                            attn_out, stats);
    kernel_ctxf<<<32 * CC_, 256, 0, stream>>>(attn_out, stats, V, cpart);
    kernel_ctx2<<<B_ * H_ * U_, 64, 0, stream>>>(cpart, Mtop, ctx_out);
}

// Round 12
// 193.842 us; speedup vs baseline: 1.0125x; 1.0125x over previous
//
#include <hip/hip_runtime.h>
#include <math.h>

// Problem constants (ProbAttention: B=4, L=4096, H=8, D=64, S=U=ceil(ln L)=9)
#define B_ 4
#define L_ 4096
#define H_ 8
#define D_ 64
#define S_ 9
#define U_ 9
#define VC_ 64   // vmean stage-1 chunks per batch
#define CC_ 16   // ctx    chunks per (b,h)  (chunk = 256 keys)
#define TKC_ 8   // topk stage-1 chunks per (b,h)
#define KCH_ 32  // scores: keys per block (all 8 heads at once)
#define NCHK_ (L_ / KCH_)           // 128 score chunks per (b,h) row
#define SCB_ (B_ * NCHK_)           // 512 scores blocks

#define VMBLK_ 256                  // vmean1 blocks (front of grid: streaming)
#define MBLK_ 4096                  // kernel_M blocks: B*L waves, 4 waves/block
#define FILLBLK_ 8192               // fill blocks

__device__ __forceinline__ float dot4(const float4& a, const float4& b) {
    return a.x * b.x + a.y * b.y + a.z * b.z + a.w * b.w;
}

// ---------------------------------------------------------------------------
// K1: fused vmean1 (blocks 0..255, streaming) + kernel_M (blocks 256..4351).
// kernel_M: one wave per (b,l); 8 heads of a K row are 2048B contiguous.
// FINAL LEDGER (r1-r11): coalescing 59->57; occupancy 25->65% 57->44;
// ILP variants (sched_barrier, asm use-fence, VGPR 32/48) invariant at
// 43.5-44.5; XCD-pinned batches: FETCH 137->125MB but time +2% -> NOT
// fetch-bound. Bound by the random 2KB-row gather service rate. Floor.
// ---------------------------------------------------------------------------
__global__ void __launch_bounds__(256, 4)
kernel_M_vmean(const float* __restrict__ Q, const float* __restrict__ K,
               const int* __restrict__ idx, float* __restrict__ M,
               const float* __restrict__ V, float* __restrict__ vpart) {
    if (blockIdx.x < VMBLK_) {
        int blk = blockIdx.x;
        int c = blk & (VC_ - 1), b = blk >> 6;
        int col = threadIdx.x & 127;
        int lp  = threadIdx.x >> 7;
        const int CHUNK = L_ / VC_;
        const float4* base = (const float4*)(V + (size_t)b * L_ * H_ * D_);
        float4 acc = make_float4(0.f, 0.f, 0.f, 0.f);
        for (int l = c * CHUNK + lp; l < (c + 1) * CHUNK; l += 2) {
            float4 v = base[(size_t)l * 128 + col];
            acc.x += v.x; acc.y += v.y; acc.z += v.z; acc.w += v.w;
        }
        __shared__ float4 red[256];
        red[threadIdx.x] = acc;
        __syncthreads();
        if (lp == 0) {
            float4 o = red[threadIdx.x + 128];
            acc.x += o.x; acc.y += o.y; acc.z += o.z; acc.w += o.w;
            ((float4*)vpart)[(size_t)blk * 128 + col] = acc;
        }
        return;
    }
    int t = threadIdx.x;
    int wid = t >> 6, lane = t & 63;
    int w = ((blockIdx.x - VMBLK_) << 2) + wid; // 0..16383 = b*L + l
    int b = __builtin_amdgcn_readfirstlane(w >> 12);
    int l = __builtin_amdgcn_readfirstlane(w & (L_ - 1));

    int ki[S_];
#pragma unroll
    for (int s = 0; s < S_; ++s) ki[s] = idx[l * S_ + s];

    const float4* qb = (const float4*)(Q + (size_t)(b * L_ + l) * (H_ * D_));
    float4 q0 = qb[2 * lane];
    float4 q1 = qb[2 * lane + 1];

    const float* Kb = K + (size_t)b * L_ * (H_ * D_);

    float4 ka[S_], kc[S_];
#pragma unroll
    for (int s = 0; s < S_; ++s) {
        const float4* kp = (const float4*)(Kb + (size_t)ki[s] * (H_ * D_));
        ka[s] = kp[2 * lane];
        kc[s] = kp[2 * lane + 1];
    }

    float mx = -INFINITY, sm = 0.0f;
#pragma unroll
    for (int s = 0; s < S_; ++s) {
        float d = dot4(q0, ka[s]) + dot4(q1, kc[s]);
        d += __shfl_xor(d, 1);
        d += __shfl_xor(d, 2);
        d += __shfl_xor(d, 4);
        mx = fmaxf(mx, d);
        sm += d;
    }
    if ((lane & 7) == 0) {
        int h = lane >> 3;
        M[((size_t)(b * H_ + h) << 12) + l] = mx - sm * (1.0f / (float)L_);
    }
}

// ---------------------------------------------------------------------------
// Top-k stage 1 (value desc, index asc) — matches jax.lax.top_k.
// 256 blocks: wide grid (r9 lesson — do NOT narrow this for launch savings).
// ---------------------------------------------------------------------------
#define CSWAP(a, b)                                                          \
    if (v[b] > v[a] || (v[b] == v[a] && id[b] < id[a])) {                    \
        float tv = v[a]; v[a] = v[b]; v[b] = tv;                             \
        int ti = id[a]; id[a] = id[b]; id[b] = ti;                           \
    }

__global__ void kernel_topk1(const float* __restrict__ M,
                             float* __restrict__ cand_v, int* __restrict__ cand_i) {
    int bh = blockIdx.x >> 3;
    int chunk = blockIdx.x & (TKC_ - 1);
    int lane = threadIdx.x;
    const float* Ms = M + ((size_t)bh << 12);

    float v[8]; int id[8];
#pragma unroll
    for (int c = 0; c < 8; ++c) {
        int gi = chunk * 512 + lane + 64 * c;
        v[c] = Ms[gi]; id[c] = gi;
    }
    CSWAP(0,1) CSWAP(2,3) CSWAP(4,5) CSWAP(6,7)
    CSWAP(0,2) CSWAP(1,3) CSWAP(4,6) CSWAP(5,7)
    CSWAP(1,2) CSWAP(5,6)
    CSWAP(0,4) CSWAP(1,5) CSWAP(2,6) CSWAP(3,7)
    CSWAP(2,4) CSWAP(3,5)
    CSWAP(1,2) CSWAP(3,4) CSWAP(5,6)

    float* cv = cand_v + (size_t)blockIdx.x * U_;
    int*   ci = cand_i + (size_t)blockIdx.x * U_;
#pragma unroll
    for (int r = 0; r < U_; ++r) {
        float bv = v[0]; int bi = id[0];
#pragma unroll
        for (int off = 1; off < 64; off <<= 1) {
            float ov = __shfl_xor(bv, off);
            int   oi = __shfl_xor(bi, off);
            if (ov > bv || (ov == bv && oi < bi)) { bv = ov; bi = oi; }
        }
        if (lane == 0) { cv[r] = bv; ci[r] = bi; }
        if (id[0] == bi) {
#pragma unroll
            for (int c = 0; c < 7; ++c) { v[c] = v[c+1]; id[c] = id[c+1]; }
            v[7] = -INFINITY; id[7] = 0x7fffffff;
        }
    }
}

// ---------------------------------------------------------------------------
// K3: fused topk2 (blocks 0..31) + vmean2 (blocks 32..63). 64 threads.
// ---------------------------------------------------------------------------
__global__ void kernel_small(const float* __restrict__ cand_v, const int* __restrict__ cand_i,
                             int* __restrict__ Mtop, const float* __restrict__ vpart,
                             float* __restrict__ vmean) {
    if (blockIdx.x >= 32) {
        int bh = blockIdx.x - 32;
        int h = bh & (H_ - 1), b = bh >> 3;
        int d = threadIdx.x;
        float s = 0.0f;
        for (int c = 0; c < VC_; ++c)
            s += vpart[(size_t)(b * VC_ + c) * (H_ * D_) + h * D_ + d];
        vmean[bh * D_ + d] = s * (1.0f / (float)L_);
        return;
    }
    int bh = blockIdx.x;
    int lane = threadIdx.x;
    const float* cv = cand_v + (size_t)bh * (TKC_ * U_);
    const int*   ci = cand_i + (size_t)bh * (TKC_ * U_);

    float v[2]; int id[2];
    v[0] = cv[lane]; id[0] = ci[lane];
    if (lane < TKC_ * U_ - 64) { v[1] = cv[64 + lane]; id[1] = ci[64 + lane]; }
    else { v[1] = -INFINITY; id[1] = 0x7fffffff; }
    CSWAP(0,1)

#pragma unroll
    for (int r = 0; r < U_; ++r) {
        float bv = v[0]; int bi = id[0];
#pragma unroll
        for (int off = 1; off < 64; off <<= 1) {
            float ov = __shfl_xor(bv, off);
            int   oi = __shfl_xor(bi, off);
            if (ov > bv || (ov == bv && oi < bi)) { bv = ov; bi = oi; }
        }
        if (lane == 0) Mtop[bh * U_ + r] = bi;
        if (id[0] == bi) { v[0] = v[1]; id[0] = id[1]; v[1] = -INFINITY; id[1] = 0x7fffffff; }
    }
}

// ---------------------------------------------------------------------------
// K4: fused fill (blocks 0..8191) + scores_raw (blocks 8192..8703).
// scores_raw: one block per (b, 32-key chunk), ALL 8 HEADS per wave (K rows
// read as contiguous 2KB). Emits per-(row,chunk) softmax stats (max, sumexp)
// so softmax finalization fuses into the ctx kernel.
// ---------------------------------------------------------------------------
__global__ void __launch_bounds__(256, 4)
kernel_fill_scores(float* __restrict__ out, const float* __restrict__ vmean,
                   const float* __restrict__ Q, const float* __restrict__ K,
                   const int* __restrict__ Mtop, float* __restrict__ raw,
                   float* __restrict__ stats) {
    if (blockIdx.x < FILLBLK_) {
        int i = blockIdx.x * 256 + threadIdx.x;
        int d4 = i & 15;
        int h  = (i >> 4) & (H_ - 1);
        int b  = i >> (4 + 3 + 12);
        ((float4*)out)[i] = ((const float4*)vmean)[(b * H_ + h) * 16 + d4];
        return;
    }
    int n = blockIdx.x - FILLBLK_;       // 0..511
    int b = n >> 7;                      // NCHK_=128 chunks per batch
    int chunk = n & 127;
    int k0 = chunk * KCH_;

    int t = threadIdx.x;
    int w = t >> 6, lane = t & 63;
    int h = lane >> 3, dq = lane & 7;
    int bh = b * H_ + h;

    float4 q0[U_], q1[U_];
#pragma unroll
    for (int u = 0; u < U_; ++u) {
        int mi = Mtop[bh * U_ + u];
        const float4* qp = (const float4*)(Q + (size_t)((b * L_ + mi) * H_ + h) * D_);
        q0[u] = qp[2 * dq];
        q1[u] = qp[2 * dq + 1];
    }

    __shared__ float sc[H_][U_][KCH_ + 1];   // +1 pad: spread h-stride over banks

    const float* Kb = K + (size_t)b * L_ * (H_ * D_);
    const float4* kp = (const float4*)(Kb + (size_t)(k0 + w * 8) * (H_ * D_));
    float4 kv0 = kp[2 * lane], kv1 = kp[2 * lane + 1];
#pragma unroll
    for (int i = 0; i < 8; ++i) {
        int kloc = w * 8 + i;
        float4 nv0, nv1;
        if (i < 7) {               // one-deep register prefetch of next row
            const float4* np = (const float4*)(Kb + (size_t)(k0 + kloc + 1) * (H_ * D_));
            nv0 = np[2 * lane]; nv1 = np[2 * lane + 1];
        }
        float p[U_];
#pragma unroll
        for (int u = 0; u < U_; ++u) {
            float d = dot4(q0[u], kv0) + dot4(q1[u], kv1);
            d += __shfl_xor(d, 1);
            d += __shfl_xor(d, 2);
            d += __shfl_xor(d, 4);
            p[u] = d;
        }
        // lane dq writes u=dq (static-index select chain, no scratch)
        float val = p[0];
#pragma unroll
        for (int u = 1; u < 8; ++u) val = (dq == u) ? p[u] : val;
        sc[h][dq][kloc] = val;
        if (dq == 0) sc[h][8][kloc] = p[8];
        kv0 = nv0; kv1 = nv1;
    }
    __syncthreads();

    // coalesced write-out: 8h*9u*32k = 2304 floats, 32-float runs per (h,u)
#pragma unroll
    for (int r = 0; r < 9; ++r) {
        int j = r * 256 + t;
        int kloc = j & 31;
        int hu = j >> 5;                 // 0..71
        int h2 = hu / U_, u2 = hu - h2 * U_;
        raw[((size_t)(b * H_ + h2) * U_ + u2) * L_ + k0 + kloc] =
            sc[h2][u2][kloc] * 0.125f;
    }

    // per-(row,chunk) softmax stats over the 32 scaled scores
    if (t < H_ * U_) {
        int h2 = t / U_, u2 = t - h2 * U_;
        float mxs = -INFINITY;
#pragma unroll
        for (int k = 0; k < KCH_; ++k) mxs = fmaxf(mxs, sc[h2][u2][k]);
        mxs *= 0.125f;
        float se = 0.0f;
#pragma unroll
        for (int k = 0; k < KCH_; ++k) se += expf(sc[h2][u2][k] * 0.125f - mxs);
        ((float2*)stats)[(size_t)((b * H_ + h2) * U_ + u2) * NCHK_ + chunk] =
            make_float2(mxs, se);
    }
}

// ---------------------------------------------------------------------------
// K6': ctx fused with SOFTMAX (replaces separate softmax + old ctxf).
// 512 blocks (wide — r9 lesson). Phase A: flash-combine 128 chunk stats per
// row -> (gmax, 1/gsum); u-loop covers row 8 (r6 fix). Phase B: attn tile =
// exp(raw-gmax)/gsum -> LDS + attn output. Phase C: ctx partials.
// ---------------------------------------------------------------------------
__global__ void kernel_ctxf(float* __restrict__ attn, const float* __restrict__ stats,
                            const float* __restrict__ V, float* __restrict__ cpart) {
    int n = blockIdx.x;
    int x = n & 7, m = n >> 3;
    int chunk = m & (CC_ - 1);
    int bh = (m >> 4) * 8 + x;       // CC_ = 16
    int h = bh & (H_ - 1), b = bh >> 3;
    int k0 = chunk * (L_ / CC_);     // 256 keys

    int t = threadIdx.x;

    // ---- Phase A: per-row global (max, 1/sum) from 128 chunk stats ----
    __shared__ float2 gstat[U_];
    int j = t & 31;
    for (int u = t >> 5; u < U_; u += 8) {   // 8 groups of 32 lanes; u=8 on 2nd pass
        const float2* srow = (const float2*)stats + (size_t)(bh * U_ + u) * NCHK_;
        float2 a = srow[j];
        float mm = a.x, ss = a.y;
#pragma unroll
        for (int c = 1; c < 4; ++c) {
            float2 b2 = srow[j + 32 * c];
            float nm = fmaxf(mm, b2.x);
            ss = ss * expf(mm - nm) + b2.y * expf(b2.x - nm);
            mm = nm;
        }
#pragma unroll
        for (int off = 1; off < 32; off <<= 1) {
            float om = __shfl_xor(mm, off, 32);
            float os = __shfl_xor(ss, off, 32);
            float nm = fmaxf(mm, om);
            ss = ss * expf(mm - nm) + os * expf(om - nm);
            mm = nm;
        }
        if (j == 0) gstat[u] = make_float2(mm, 1.0f / ss);
    }
    __syncthreads();

    // ---- Phase B: materialize attn tile (9 x 256) in LDS + write output ----
    __shared__ float attn_s[U_][256];
    float* arow = attn + (size_t)bh * U_ * L_ + k0;
#pragma unroll
    for (int u = 0; u < U_; ++u) {
        float xv = arow[(size_t)u * L_ + t];
        float av = expf(xv - gstat[u].x) * gstat[u].y;
        attn_s[u][t] = av;
        arow[(size_t)u * L_ + t] = av;
    }
    __syncthreads();

    // ---- Phase C: ctx partial accumulation (attn from LDS broadcast) ----
    int g = t >> 6, lane = t & 63;
    int kl = lane >> 4, d4 = lane & 15;

    float4 acc[U_];
#pragma unroll
    for (int u = 0; u < U_; ++u) acc[u] = make_float4(0.f, 0.f, 0.f, 0.f);

    for (int i = 0; i < 16; ++i) {
        int kloc = (g * 4 + kl) + 16 * i;
        int k = k0 + kloc;
        float4 vv = *(const float4*)(V + (size_t)((b * L_ + k) * H_ + h) * D_ + 4 * d4);
        float av[U_];
#pragma unroll
        for (int u = 0; u < U_; ++u) av[u] = attn_s[u][kloc];
#pragma unroll
        for (int u = 0; u < U_; ++u) {
            acc[u].x += av[u] * vv.x; acc[u].y += av[u] * vv.y;
            acc[u].z += av[u] * vv.z; acc[u].w += av[u] * vv.w;
        }
    }
    // reduce over kl (lanes 16,32 apart)
#pragma unroll
    for (int u = 0; u < U_; ++u) {
        acc[u].x += __shfl_xor(acc[u].x, 16); acc[u].y += __shfl_xor(acc[u].y, 16);
        acc[u].z += __shfl_xor(acc[u].z, 16); acc[u].w += __shfl_xor(acc[u].w, 16);
        acc[u].x += __shfl_xor(acc[u].x, 32); acc[u].y += __shfl_xor(acc[u].y, 32);
        acc[u].z += __shfl_xor(acc[u].z, 32); acc[u].w += __shfl_xor(acc[u].w, 32);
    }
    __shared__ float4 red[U_][4][16];
    if (kl == 0) {
#pragma unroll
        for (int u = 0; u < U_; ++u) red[u][g][d4] = acc[u];
    }
    __syncthreads();
    if (t < U_ * 16) {
        int u = t >> 4, dd = t & 15;
        float4 s0 = red[u][0][dd], s1 = red[u][1][dd];
        float4 s2 = red[u][2][dd], s3 = red[u][3][dd];
        float4 s = make_float4(s0.x + s1.x + s2.x + s3.x, s0.y + s1.y + s2.y + s3.y,
                               s0.z + s1.z + s2.z + s3.z, s0.w + s1.w + s2.w + s3.w);
        ((float4*)cpart)[((size_t)(bh * CC_ + chunk) * U_ + u) * 16 + dd] = s;
    }
}

// K7: combine + scatter. grid = B*H*U (288), 64 threads.
__global__ void kernel_ctx2(const float* __restrict__ cpart, const int* __restrict__ Mtop,
                            float* __restrict__ out) {
    int row = blockIdx.x;
    int u = row % U_, bh = row / U_;
    int h = bh & (H_ - 1), b = bh >> 3;
    int d = threadIdx.x;
    float s = 0.0f;
#pragma unroll
    for (int c = 0; c < CC_; ++c)
        s += cpart[((size_t)(bh * CC_ + c) * U_ + u) * 64 + d];
    int l = Mtop[bh * U_ + u];
    out[(size_t)((b * L_ + l) * H_ + h) * D_ + d] = s;
}

extern "C" void kernel_launch(void* const* d_in, const int* in_sizes, int n_in,
                              void* d_out, int out_size, void* d_ws, size_t ws_size,
                              hipStream_t stream) {
    const float* Q   = (const float*)d_in[0];
    const float* K   = (const float*)d_in[1];
    const float* V   = (const float*)d_in[2];
    const int*   idx = (const int*)d_in[3];

    float* ctx_out  = (float*)d_out;                               // B*L*H*D
    float* attn_out = (float*)d_out + (size_t)B_ * L_ * H_ * D_;   // B*H*U*L

    // workspace (floats): M | vpart | vmean | cpart | cand_v | cand_i | Mtop | stats
    float* M      = (float*)d_ws;                                   // 131072
    float* vpart  = M + (size_t)B_ * H_ * L_;                       // 131072
    float* vmean  = vpart + (size_t)B_ * VC_ * H_ * D_;             // 2048
    float* cpart  = vmean + B_ * H_ * D_;                           // 294912
    float* cand_v = cpart + (size_t)32 * CC_ * U_ * 64;             // 2304
    int*   cand_i = (int*)(cand_v + 32 * TKC_ * U_);                // 2304
    int*   Mtop   = cand_i + 32 * TKC_ * U_;                        // 288
    float* stats  = (float*)(Mtop + 32 * U_);                       // 73728

    kernel_M_vmean<<<VMBLK_ + MBLK_, 256, 0, stream>>>(Q, K, idx, M, V, vpart);
    kernel_topk1<<<B_ * H_ * TKC_, 64, 0, stream>>>(M, cand_v, cand_i);
    kernel_small<<<64, 64, 0, stream>>>(cand_v, cand_i, Mtop, vpart, vmean);
    kernel_fill_scores<<<FILLBLK_ + SCB_, 256, 0, stream>>>(ctx_out, vmean, Q, K, Mtop,
                                                            attn_out, stats);
    kernel_ctxf<<<32 * CC_, 256, 0, stream>>>(attn_out, stats, V, cpart);
    kernel_ctx2<<<B_ * H_ * U_, 64, 0, stream>>>(cpart, Mtop, ctx_out);
}

// Round 13
// 190.938 us; speedup vs baseline: 1.0279x; 1.0152x over previous
//
#include <hip/hip_runtime.h>
#include <math.h>

// Problem constants (ProbAttention: B=4, L=4096, H=8, D=64, S=U=ceil(ln L)=9)
#define B_ 4
#define L_ 4096
#define H_ 8
#define D_ 64
#define S_ 9
#define U_ 9
#define VC_ 64   // vmean stage-1 chunks per batch
#define CC_ 16   // ctx    chunks per (b,h)  (chunk = 256 keys)
#define TKC_ 8   // topk stage-1 chunks per (b,h)
#define KCH_ 32  // scores: keys per block (all 8 heads at once)
#define NCHK_ (L_ / KCH_)           // 128 score chunks per (b,h) row
#define SCB_ (B_ * NCHK_)           // 512 scores blocks

#define VMBLK_ 256                  // vmean1 blocks (front of grid: streaming)
#define MBLK_ 4096                  // kernel_M blocks: B*L waves, 4 waves/block
#define FILLB_ 2048                 // fill blocks (grid-stride x4)

__device__ __forceinline__ float dot4(const float4& a, const float4& b) {
    return a.x * b.x + a.y * b.y + a.z * b.z + a.w * b.w;
}

// ---------------------------------------------------------------------------
// K1: fused vmean1 (blocks 0..255, streaming) + kernel_M (blocks 256..4351).
// kernel_M: one wave per (b,l); 8 heads of a K row are 2048B contiguous.
// LEDGER (r1-r11): coalescing 59->57; occupancy 25->65% 57->44; ILP variants
// invariant 43.5-44.5; XCD-pinning: FETCH -9% but time +2% -> NOT fetch-
// bound. Random 2KB-row gather service-rate floor.
// r12: fill_scores surfaced at 43.8us (occ 18%, nothing saturated) ->
// SPLIT fill/scores this round for localization + occupancy fix.
// ---------------------------------------------------------------------------
__global__ void __launch_bounds__(256, 4)
kernel_M_vmean(const float* __restrict__ Q, const float* __restrict__ K,
               const int* __restrict__ idx, float* __restrict__ M,
               const float* __restrict__ V, float* __restrict__ vpart) {
    if (blockIdx.x < VMBLK_) {
        int blk = blockIdx.x;
        int c = blk & (VC_ - 1), b = blk >> 6;
        int col = threadIdx.x & 127;
        int lp  = threadIdx.x >> 7;
        const int CHUNK = L_ / VC_;
        const float4* base = (const float4*)(V + (size_t)b * L_ * H_ * D_);
        float4 acc = make_float4(0.f, 0.f, 0.f, 0.f);
        for (int l = c * CHUNK + lp; l < (c + 1) * CHUNK; l += 2) {
            float4 v = base[(size_t)l * 128 + col];
            acc.x += v.x; acc.y += v.y; acc.z += v.z; acc.w += v.w;
        }
        __shared__ float4 red[256];
        red[threadIdx.x] = acc;
        __syncthreads();
        if (lp == 0) {
            float4 o = red[threadIdx.x + 128];
            acc.x += o.x; acc.y += o.y; acc.z += o.z; acc.w += o.w;
            ((float4*)vpart)[(size_t)blk * 128 + col] = acc;
        }
        return;
    }
    int t = threadIdx.x;
    int wid = t >> 6, lane = t & 63;
    int w = ((blockIdx.x - VMBLK_) << 2) + wid; // 0..16383 = b*L + l
    int b = __builtin_amdgcn_readfirstlane(w >> 12);
    int l = __builtin_amdgcn_readfirstlane(w & (L_ - 1));

    int ki[S_];
#pragma unroll
    for (int s = 0; s < S_; ++s) ki[s] = idx[l * S_ + s];

    const float4* qb = (const float4*)(Q + (size_t)(b * L_ + l) * (H_ * D_));
    float4 q0 = qb[2 * lane];
    float4 q1 = qb[2 * lane + 1];

    const float* Kb = K + (size_t)b * L_ * (H_ * D_);

    float4 ka[S_], kc[S_];
#pragma unroll
    for (int s = 0; s < S_; ++s) {
        const float4* kp = (const float4*)(Kb + (size_t)ki[s] * (H_ * D_));
        ka[s] = kp[2 * lane];
        kc[s] = kp[2 * lane + 1];
    }

    float mx = -INFINITY, sm = 0.0f;
#pragma unroll
    for (int s = 0; s < S_; ++s) {
        float d = dot4(q0, ka[s]) + dot4(q1, kc[s]);
        d += __shfl_xor(d, 1);
        d += __shfl_xor(d, 2);
        d += __shfl_xor(d, 4);
        mx = fmaxf(mx, d);
        sm += d;
    }
    if ((lane & 7) == 0) {
        int h = lane >> 3;
        M[((size_t)(b * H_ + h) << 12) + l] = mx - sm * (1.0f / (float)L_);
    }
}

// ---------------------------------------------------------------------------
// Top-k stage 1 (value desc, index asc) — matches jax.lax.top_k.
// 256 blocks: wide grid (r9 lesson — do NOT narrow this for launch savings).
// ---------------------------------------------------------------------------
#define CSWAP(a, b)                                                          \
    if (v[b] > v[a] || (v[b] == v[a] && id[b] < id[a])) {                    \
        float tv = v[a]; v[a] = v[b]; v[b] = tv;                             \
        int ti = id[a]; id[a] = id[b]; id[b] = ti;                           \
    }

__global__ void kernel_topk1(const float* __restrict__ M,
                             float* __restrict__ cand_v, int* __restrict__ cand_i) {
    int bh = blockIdx.x >> 3;
    int chunk = blockIdx.x & (TKC_ - 1);
    int lane = threadIdx.x;
    const float* Ms = M + ((size_t)bh << 12);

    float v[8]; int id[8];
#pragma unroll
    for (int c = 0; c < 8; ++c) {
        int gi = chunk * 512 + lane + 64 * c;
        v[c] = Ms[gi]; id[c] = gi;
    }
    CSWAP(0,1) CSWAP(2,3) CSWAP(4,5) CSWAP(6,7)
    CSWAP(0,2) CSWAP(1,3) CSWAP(4,6) CSWAP(5,7)
    CSWAP(1,2) CSWAP(5,6)
    CSWAP(0,4) CSWAP(1,5) CSWAP(2,6) CSWAP(3,7)
    CSWAP(2,4) CSWAP(3,5)
    CSWAP(1,2) CSWAP(3,4) CSWAP(5,6)

    float* cv = cand_v + (size_t)blockIdx.x * U_;
    int*   ci = cand_i + (size_t)blockIdx.x * U_;
#pragma unroll
    for (int r = 0; r < U_; ++r) {
        float bv = v[0]; int bi = id[0];
#pragma unroll
        for (int off = 1; off < 64; off <<= 1) {
            float ov = __shfl_xor(bv, off);
            int   oi = __shfl_xor(bi, off);
            if (ov > bv || (ov == bv && oi < bi)) { bv = ov; bi = oi; }
        }
        if (lane == 0) { cv[r] = bv; ci[r] = bi; }
        if (id[0] == bi) {
#pragma unroll
            for (int c = 0; c < 7; ++c) { v[c] = v[c+1]; id[c] = id[c+1]; }
            v[7] = -INFINITY; id[7] = 0x7fffffff;
        }
    }
}

// ---------------------------------------------------------------------------
// K3: fused topk2 (blocks 0..31) + vmean2 (blocks 32..63). 64 threads.
// ---------------------------------------------------------------------------
__global__ void kernel_small(const float* __restrict__ cand_v, const int* __restrict__ cand_i,
                             int* __restrict__ Mtop, const float* __restrict__ vpart,
                             float* __restrict__ vmean) {
    if (blockIdx.x >= 32) {
        int bh = blockIdx.x - 32;
        int h = bh & (H_ - 1), b = bh >> 3;
        int d = threadIdx.x;
        float s = 0.0f;
        for (int c = 0; c < VC_; ++c)
            s += vpart[(size_t)(b * VC_ + c) * (H_ * D_) + h * D_ + d];
        vmean[bh * D_ + d] = s * (1.0f / (float)L_);
        return;
    }
    int bh = blockIdx.x;
    int lane = threadIdx.x;
    const float* cv = cand_v + (size_t)bh * (TKC_ * U_);
    const int*   ci = cand_i + (size_t)bh * (TKC_ * U_);

    float v[2]; int id[2];
    v[0] = cv[lane]; id[0] = ci[lane];
    if (lane < TKC_ * U_ - 64) { v[1] = cv[64 + lane]; id[1] = ci[64 + lane]; }
    else { v[1] = -INFINITY; id[1] = 0x7fffffff; }
    CSWAP(0,1)

#pragma unroll
    for (int r = 0; r < U_; ++r) {
        float bv = v[0]; int bi = id[0];
#pragma unroll
        for (int off = 1; off < 64; off <<= 1) {
            float ov = __shfl_xor(bv, off);
            int   oi = __shfl_xor(bi, off);
            if (ov > bv || (ov == bv && oi < bi)) { bv = ov; bi = oi; }
        }
        if (lane == 0) Mtop[bh * U_ + r] = bi;
        if (id[0] == bi) { v[0] = v[1]; id[0] = id[1]; v[1] = -INFINITY; id[1] = 0x7fffffff; }
    }
}

// ---------------------------------------------------------------------------
// K4a: fill ONLY (split from scores, r12). 2048 blocks x 256 thr, 4x
// grid-stride: 4 independent vmean loads + 4 coalesced stores per thread
// (4x MLP vs the old 1-float4-per-thread block). No LDS -> full occupancy.
// ---------------------------------------------------------------------------
__global__ void __launch_bounds__(256)
kernel_fill(float* __restrict__ out, const float* __restrict__ vmean) {
    int i0 = blockIdx.x * 1024 + threadIdx.x;
    const float4* vm4 = (const float4*)vmean;
#pragma unroll
    for (int j = 0; j < 4; ++j) {
        int i = i0 + j * 256;
        int d4 = i & 15;
        int h  = (i >> 4) & (H_ - 1);
        int b  = i >> 19;
        ((float4*)out)[i] = vm4[(b * H_ + h) * 16 + d4];
    }
}

// ---------------------------------------------------------------------------
// K4b: scores ONLY (split from fill, r12 — logic byte-identical to the
// scores half of the old fused kernel). One block per (b, 32-key chunk),
// all 8 heads per wave; K rows read as contiguous 2KB; emits per-(row,chunk)
// softmax stats (max, sumexp).
// ---------------------------------------------------------------------------
__global__ void __launch_bounds__(256, 4)
kernel_scores(const float* __restrict__ Q, const float* __restrict__ K,
              const int* __restrict__ Mtop, float* __restrict__ raw,
              float* __restrict__ stats) {
    int n = blockIdx.x;                  // 0..511
    int b = n >> 7;                      // NCHK_=128 chunks per batch
    int chunk = n & 127;
    int k0 = chunk * KCH_;

    int t = threadIdx.x;
    int w = t >> 6, lane = t & 63;
    int h = lane >> 3, dq = lane & 7;
    int bh = b * H_ + h;

    float4 q0[U_], q1[U_];
#pragma unroll
    for (int u = 0; u < U_; ++u) {
        int mi = Mtop[bh * U_ + u];
        const float4* qp = (const float4*)(Q + (size_t)((b * L_ + mi) * H_ + h) * D_);
        q0[u] = qp[2 * dq];
        q1[u] = qp[2 * dq + 1];
    }

    __shared__ float sc[H_][U_][KCH_ + 1];   // +1 pad: spread h-stride over banks

    const float* Kb = K + (size_t)b * L_ * (H_ * D_);
    const float4* kp = (const float4*)(Kb + (size_t)(k0 + w * 8) * (H_ * D_));
    float4 kv0 = kp[2 * lane], kv1 = kp[2 * lane + 1];
#pragma unroll
    for (int i = 0; i < 8; ++i) {
        int kloc = w * 8 + i;
        float4 nv0, nv1;
        if (i < 7) {               // one-deep register prefetch of next row
            const float4* np = (const float4*)(Kb + (size_t)(k0 + kloc + 1) * (H_ * D_));
            nv0 = np[2 * lane]; nv1 = np[2 * lane + 1];
        }
        float p[U_];
#pragma unroll
        for (int u = 0; u < U_; ++u) {
            float d = dot4(q0[u], kv0) + dot4(q1[u], kv1);
            d += __shfl_xor(d, 1);
            d += __shfl_xor(d, 2);
            d += __shfl_xor(d, 4);
            p[u] = d;
        }
        // lane dq writes u=dq (static-index select chain, no scratch)
        float val = p[0];
#pragma unroll
        for (int u = 1; u < 8; ++u) val = (dq == u) ? p[u] : val;
        sc[h][dq][kloc] = val;
        if (dq == 0) sc[h][8][kloc] = p[8];
        kv0 = nv0; kv1 = nv1;
    }
    __syncthreads();

    // coalesced write-out: 8h*9u*32k = 2304 floats, 32-float runs per (h,u)
#pragma unroll
    for (int r = 0; r < 9; ++r) {
        int j = r * 256 + t;
        int kloc = j & 31;
        int hu = j >> 5;                 // 0..71
        int h2 = hu / U_, u2 = hu - h2 * U_;
        raw[((size_t)(b * H_ + h2) * U_ + u2) * L_ + k0 + kloc] =
            sc[h2][u2][kloc] * 0.125f;
    }

    // per-(row,chunk) softmax stats over the 32 scaled scores
    if (t < H_ * U_) {
        int h2 = t / U_, u2 = t - h2 * U_;
        float mxs = -INFINITY;
#pragma unroll
        for (int k = 0; k < KCH_; ++k) mxs = fmaxf(mxs, sc[h2][u2][k]);
        mxs *= 0.125f;
        float se = 0.0f;
#pragma unroll
        for (int k = 0; k < KCH_; ++k) se += expf(sc[h2][u2][k] * 0.125f - mxs);
        ((float2*)stats)[(size_t)((b * H_ + h2) * U_ + u2) * NCHK_ + chunk] =
            make_float2(mxs, se);
    }
}

// ---------------------------------------------------------------------------
// K6': ctx fused with SOFTMAX. 512 blocks (wide — r9 lesson). Phase A:
// flash-combine 128 chunk stats per row -> (gmax, 1/gsum); u-loop covers
// row 8 (r6 fix). Phase B: attn tile -> LDS + attn output. Phase C: ctx.
// ---------------------------------------------------------------------------
__global__ void kernel_ctxf(float* __restrict__ attn, const float* __restrict__ stats,
                            const float* __restrict__ V, float* __restrict__ cpart) {
    int n = blockIdx.x;
    int x = n & 7, m = n >> 3;
    int chunk = m & (CC_ - 1);
    int bh = (m >> 4) * 8 + x;       // CC_ = 16
    int h = bh & (H_ - 1), b = bh >> 3;
    int k0 = chunk * (L_ / CC_);     // 256 keys

    int t = threadIdx.x;

    // ---- Phase A: per-row global (max, 1/sum) from 128 chunk stats ----
    __shared__ float2 gstat[U_];
    int j = t & 31;
    for (int u = t >> 5; u < U_; u += 8) {   // 8 groups of 32 lanes; u=8 on 2nd pass
        const float2* srow = (const float2*)stats + (size_t)(bh * U_ + u) * NCHK_;
        float2 a = srow[j];
        float mm = a.x, ss = a.y;
#pragma unroll
        for (int c = 1; c < 4; ++c) {
            float2 b2 = srow[j + 32 * c];
            float nm = fmaxf(mm, b2.x);
            ss = ss * expf(mm - nm) + b2.y * expf(b2.x - nm);
            mm = nm;
        }
#pragma unroll
        for (int off = 1; off < 32; off <<= 1) {
            float om = __shfl_xor(mm, off, 32);
            float os = __shfl_xor(ss, off, 32);
            float nm = fmaxf(mm, om);
            ss = ss * expf(mm - nm) + os * expf(om - nm);
            mm = nm;
        }
        if (j == 0) gstat[u] = make_float2(mm, 1.0f / ss);
    }
    __syncthreads();

    // ---- Phase B: materialize attn tile (9 x 256) in LDS + write output ----
    __shared__ float attn_s[U_][256];
    float* arow = attn + (size_t)bh * U_ * L_ + k0;
#pragma unroll
    for (int u = 0; u < U_; ++u) {
        float xv = arow[(size_t)u * L_ + t];
        float av = expf(xv - gstat[u].x) * gstat[u].y;
        attn_s[u][t] = av;
        arow[(size_t)u * L_ + t] = av;
    }
    __syncthreads();

    // ---- Phase C: ctx partial accumulation (attn from LDS broadcast) ----
    int g = t >> 6, lane = t & 63;
    int kl = lane >> 4, d4 = lane & 15;

    float4 acc[U_];
#pragma unroll
    for (int u = 0; u < U_; ++u) acc[u] = make_float4(0.f, 0.f, 0.f, 0.f);

    for (int i = 0; i < 16; ++i) {
        int kloc = (g * 4 + kl) + 16 * i;
        int k = k0 + kloc;
        float4 vv = *(const float4*)(V + (size_t)((b * L_ + k) * H_ + h) * D_ + 4 * d4);
        float av[U_];
#pragma unroll
        for (int u = 0; u < U_; ++u) av[u] = attn_s[u][kloc];
#pragma unroll
        for (int u = 0; u < U_; ++u) {
            acc[u].x += av[u] * vv.x; acc[u].y += av[u] * vv.y;
            acc[u].z += av[u] * vv.z; acc[u].w += av[u] * vv.w;
        }
    }
    // reduce over kl (lanes 16,32 apart)
#pragma unroll
    for (int u = 0; u < U_; ++u) {
        acc[u].x += __shfl_xor(acc[u].x, 16); acc[u].y += __shfl_xor(acc[u].y, 16);
        acc[u].z += __shfl_xor(acc[u].z, 16); acc[u].w += __shfl_xor(acc[u].w, 16);
        acc[u].x += __shfl_xor(acc[u].x, 32); acc[u].y += __shfl_xor(acc[u].y, 32);
        acc[u].z += __shfl_xor(acc[u].z, 32); acc[u].w += __shfl_xor(acc[u].w, 32);
    }
    __shared__ float4 red[U_][4][16];
    if (kl == 0) {
#pragma unroll
        for (int u = 0; u < U_; ++u) red[u][g][d4] = acc[u];
    }
    __syncthreads();
    if (t < U_ * 16) {
        int u = t >> 4, dd = t & 15;
        float4 s0 = red[u][0][dd], s1 = red[u][1][dd];
        float4 s2 = red[u][2][dd], s3 = red[u][3][dd];
        float4 s = make_float4(s0.x + s1.x + s2.x + s3.x, s0.y + s1.y + s2.y + s3.y,
                               s0.z + s1.z + s2.z + s3.z, s0.w + s1.w + s2.w + s3.w);
        ((float4*)cpart)[((size_t)(bh * CC_ + chunk) * U_ + u) * 16 + dd] = s;
    }
}

// K7: combine + scatter. grid = B*H*U (288), 64 threads.
__global__ void kernel_ctx2(const float* __restrict__ cpart, const int* __restrict__ Mtop,
                            float* __restrict__ out) {
    int row = blockIdx.x;
    int u = row % U_, bh = row / U_;
    int h = bh & (H_ - 1), b = bh >> 3;
    int d = threadIdx.x;
    float s = 0.0f;
#pragma unroll
    for (int c = 0; c < CC_; ++c)
        s += cpart[((size_t)(bh * CC_ + c) * U_ + u) * 64 + d];
    int l = Mtop[bh * U_ + u];
    out[(size_t)((b * L_ + l) * H_ + h) * D_ + d] = s;
}

extern "C" void kernel_launch(void* const* d_in, const int* in_sizes, int n_in,
                              void* d_out, int out_size, void* d_ws, size_t ws_size,
                              hipStream_t stream) {
    const float* Q   = (const float*)d_in[0];
    const float* K   = (const float*)d_in[1];
    const float* V   = (const float*)d_in[2];
    const int*   idx = (const int*)d_in[3];

    float* ctx_out  = (float*)d_out;                               // B*L*H*D
    float* attn_out = (float*)d_out + (size_t)B_ * L_ * H_ * D_;   // B*H*U*L

    // workspace (floats): M | vpart | vmean | cpart | cand_v | cand_i | Mtop | stats
    float* M      = (float*)d_ws;                                   // 131072
    float* vpart  = M + (size_t)B_ * H_ * L_;                       // 131072
    float* vmean  = vpart + (size_t)B_ * VC_ * H_ * D_;             // 2048
    float* cpart  = vmean + B_ * H_ * D_;                           // 294912
    float* cand_v = cpart + (size_t)32 * CC_ * U_ * 64;             // 2304
    int*   cand_i = (int*)(cand_v + 32 * TKC_ * U_);                // 2304
    int*   Mtop   = cand_i + 32 * TKC_ * U_;                        // 288
    float* stats  = (float*)(Mtop + 32 * U_);                       // 73728

    kernel_M_vmean<<<VMBLK_ + MBLK_, 256, 0, stream>>>(Q, K, idx, M, V, vpart);
    kernel_topk1<<<B_ * H_ * TKC_, 64, 0, stream>>>(M, cand_v, cand_i);
    kernel_small<<<64, 64, 0, stream>>>(cand_v, cand_i, Mtop, vpart, vmean);
    kernel_fill<<<FILLB_, 256, 0, stream>>>(ctx_out, vmean);
    kernel_scores<<<SCB_, 256, 0, stream>>>(Q, K, Mtop, attn_out, stats);
    kernel_ctxf<<<32 * CC_, 256, 0, stream>>>(attn_out, stats, V, cpart);
    kernel_ctx2<<<B_ * H_ * U_, 64, 0, stream>>>(cpart, Mtop, ctx_out);
}